// Round 1
// 146.587 us; speedup vs baseline: 1.1477x; 1.1477x over previous
//
#include <hip/hip_runtime.h>

#define D_FEAT 128
#define MAX_CHUNK 1024

// ---------------------------------------------------------------------------
// Fused prep (UNCHANGED from baseline — known good).
//   Blocks [0, qb):  per-row int8 quantization. 4 waves/block, one node row
//                    per wave: load 128 fp32 (float2/lane), butterfly absmax,
//                    q = rint(x * 127/absmax), write 128 B row + fp32 scale.
//   Blocks [qb, ..): segment offsets from the sorted macro ids.
__global__ __launch_bounds__(256)
void prep_kernel(const float* __restrict__ feat,
                 unsigned char* __restrict__ tab, float* __restrict__ scales,
                 int n_nodes, int qb,
                 const int* __restrict__ mids, int n_gather,
                 int num_macro, int* __restrict__ offsets) {
    if ((int)blockIdx.x < qb) {
        const int wave = threadIdx.x >> 6;
        const int lane = threadIdx.x & 63;
        const int row  = blockIdx.x * 4 + wave;
        if (row >= n_nodes) return;
        const float2 v = ((const float2*)feat)[(size_t)row * 64 + lane];
        float a = fmaxf(fabsf(v.x), fabsf(v.y));
        #pragma unroll
        for (int d = 1; d <= 32; d <<= 1) a = fmaxf(a, __shfl_xor(a, d, 64));
        const float inv = (a > 0.f) ? (127.f / a) : 0.f;
        const int q0 = (int)rintf(v.x * inv);
        const int q1 = (int)rintf(v.y * inv);
        const unsigned short p =
            (unsigned short)((q0 & 0xFF) | ((q1 & 0xFF) << 8));
        ((unsigned short*)tab)[(size_t)row * 64 + lane] = p;   // 128 B/row
        if (lane == 0) scales[row] = a * (1.f / 127.f);
    } else {
        const int i = ((int)blockIdx.x - qb) * 256 + (int)threadIdx.x;
        if (i >= n_gather) return;
        const int cur  = mids[i];
        const int prev = (i == 0) ? -1 : mids[i - 1];
        for (int m = prev + 1; m <= cur; ++m) offsets[m] = i;
        if (i == n_gather - 1) {
            for (int m = cur + 1; m <= num_macro; ++m) offsets[m] = n_gather;
        }
    }
}

// ---------------------------------------------------------------------------
// Pool v2: scalar-addressed int8 gather, ONE WAVE per macro node.
//
// Theory: v1 was latency-bound (HBM 21%, VALU 37%, occ 66%) with MLP ~12
// misses/CU — every row address sat behind a ds_bpermute chain and only 8
// loads were in flight per wave. v2 removes LDS permutes entirely:
//   - one coalesced 64-index load per chunk (vector, as before),
//   - per row: v_readlane (idx -> SGPR) + uniform base arithmetic +
//     global_load_ushort with FIXED per-lane offset (lane*2 into a 128 B
//     row => still exactly 1 cache line per row, same FETCH profile),
//   - scale via uniform load scales[idx] (s_load, 400 KB array, L2-hit),
//   - 32-deep load batches: a typical segment (cnt≈32) issues ALL its row
//     loads back-to-back before the first dequant consumes.
// Per row per lane: 2 features, bfe+cvt+fmac each; no LDS, no barriers.
__global__ __launch_bounds__(256)
void pool_wave_i8_v2_kernel(const unsigned char* __restrict__ tab,
                            const float* __restrict__ scales,
                            const int* __restrict__ nids,
                            const int* __restrict__ offsets,
                            float* __restrict__ out, int num_macro) {
    const int wave = threadIdx.x >> 6;
    const int m    = blockIdx.x * 4 + wave;
    if (m >= num_macro) return;

    const int lane  = threadIdx.x & 63;
    const int lane2 = lane << 1;            // byte offset within a 128 B row

    const int start = offsets[m];
    const int cnt   = offsets[m + 1] - start;

    float ax = 0.f, ay = 0.f;

    for (int b0 = 0; b0 < cnt; b0 += 64) {
        const int rem = min(cnt - b0, 64);
        // one coalesced load of up to 64 indices (clamped lanes stay valid)
        const int my = nids[start + b0 + ((lane < rem) ? lane : rem - 1)];

        int k = 0;
        // 32-deep super-step: 32 row loads + 32 scale loads in flight
        for (; k + 32 <= rem; k += 32) {
            unsigned int w[32];
            float        s[32];
            #pragma unroll
            for (int j = 0; j < 32; ++j) {
                const int idx = __builtin_amdgcn_readlane(my, k + j);
                w[j] = *(const unsigned short*)(tab + ((size_t)idx << 7) + lane2);
                s[j] = scales[idx];
            }
            #pragma unroll
            for (int j = 0; j < 32; ++j) {
                ax += s[j] * (float)(signed char)(w[j] & 0xFF);
                ay += s[j] * (float)(signed char)(w[j] >> 8);
            }
        }
        // 8-deep tail
        for (; k + 8 <= rem; k += 8) {
            unsigned int w[8];
            float        s[8];
            #pragma unroll
            for (int j = 0; j < 8; ++j) {
                const int idx = __builtin_amdgcn_readlane(my, k + j);
                w[j] = *(const unsigned short*)(tab + ((size_t)idx << 7) + lane2);
                s[j] = scales[idx];
            }
            #pragma unroll
            for (int j = 0; j < 8; ++j) {
                ax += s[j] * (float)(signed char)(w[j] & 0xFF);
                ay += s[j] * (float)(signed char)(w[j] >> 8);
            }
        }
        // scalar tail
        for (; k < rem; ++k) {
            const int idx = __builtin_amdgcn_readlane(my, k);
            const unsigned int w =
                *(const unsigned short*)(tab + ((size_t)idx << 7) + lane2);
            const float s = scales[idx];
            ax += s * (float)(signed char)(w & 0xFF);
            ay += s * (float)(signed char)(w >> 8);
        }
    }

    const float inv = (cnt > 0) ? (1.0f / (float)cnt) : 0.0f;
    // 64 lanes x 8 B = 512 B coalesced row write
    *(float2*)(out + (size_t)m * D_FEAT + lane2) = make_float2(ax * inv, ay * inv);
}

// ---------------------------------------------------------------------------
// Fallback (fp32 table, no shadow) — only if ws_size can't hold the tables.
__global__ __launch_bounds__(256)
void pool_mean_fp32_kernel(const float* __restrict__ feat,
                           const int* __restrict__ nids,
                           const int* __restrict__ offsets,
                           float* __restrict__ out) {
    const int m    = blockIdx.x;
    const int tid  = threadIdx.x;
    const int g    = tid >> 5;
    const int c4   = (tid & 31) << 2;

    const int start = offsets[m];
    const int cnt   = offsets[m + 1] - start;

    __shared__ int   s_idx[MAX_CHUNK];
    __shared__ float red[8][D_FEAT];

    float4 acc = make_float4(0.f, 0.f, 0.f, 0.f);
    for (int base = 0; base < cnt; base += MAX_CHUNK) {
        const int chunk = min(cnt - base, MAX_CHUNK);
        for (int t = tid; t < chunk; t += 256) s_idx[t] = nids[start + base + t];
        __syncthreads();
        int r = g;
        for (; r + 24 < chunk; r += 32) {
            const float4 v0 = *(const float4*)(feat + (size_t)s_idx[r]      * D_FEAT + c4);
            const float4 v1 = *(const float4*)(feat + (size_t)s_idx[r + 8]  * D_FEAT + c4);
            const float4 v2 = *(const float4*)(feat + (size_t)s_idx[r + 16] * D_FEAT + c4);
            const float4 v3 = *(const float4*)(feat + (size_t)s_idx[r + 24] * D_FEAT + c4);
            acc.x += v0.x + v1.x + v2.x + v3.x;
            acc.y += v0.y + v1.y + v2.y + v3.y;
            acc.z += v0.z + v1.z + v2.z + v3.z;
            acc.w += v0.w + v1.w + v2.w + v3.w;
        }
        for (; r < chunk; r += 8) {
            const float4 v = *(const float4*)(feat + (size_t)s_idx[r] * D_FEAT + c4);
            acc.x += v.x; acc.y += v.y; acc.z += v.z; acc.w += v.w;
        }
        __syncthreads();
    }

    red[g][c4 + 0] = acc.x;
    red[g][c4 + 1] = acc.y;
    red[g][c4 + 2] = acc.z;
    red[g][c4 + 3] = acc.w;
    __syncthreads();

    if (tid < D_FEAT) {
        float s = 0.f;
        #pragma unroll
        for (int k = 0; k < 8; ++k) s += red[k][tid];
        const float inv = (cnt > 0) ? (1.0f / (float)cnt) : 0.0f;
        out[(size_t)m * D_FEAT + tid] = s * inv;
    }
}

// Offsets-only prep for the fallback path.
__global__ __launch_bounds__(256)
void seg_offsets_kernel(const int* __restrict__ mids, int n_gather,
                        int num_macro, int* __restrict__ offsets) {
    const int i = blockIdx.x * blockDim.x + threadIdx.x;
    if (i >= n_gather) return;
    const int cur  = mids[i];
    const int prev = (i == 0) ? -1 : mids[i - 1];
    for (int m = prev + 1; m <= cur; ++m) offsets[m] = i;
    if (i == n_gather - 1) {
        for (int m = cur + 1; m <= num_macro; ++m) offsets[m] = n_gather;
    }
}

extern "C" void kernel_launch(void* const* d_in, const int* in_sizes, int n_in,
                              void* d_out, int out_size, void* d_ws, size_t ws_size,
                              hipStream_t stream) {
    const float* feat = (const float*)d_in[0];   // [n_nodes, 128] fp32
    const int*   nids = (const int*)d_in[1];     // [n_gather] int32
    const int*   mids = (const int*)d_in[2];     // [n_gather] int32, sorted
    float*       out  = (float*)d_out;           // [num_macro, 128] fp32

    const int n_gather  = in_sizes[1];
    const int num_macro = out_size / D_FEAT;
    const int n_nodes   = in_sizes[0] / D_FEAT;

    // d_ws: [offsets (num_macro+1) ints][scales n_nodes fp32][int8 table], 256-aligned
    int* offsets = (int*)d_ws;
    const size_t off_bytes   = ((size_t)(num_macro + 1) * sizeof(int) + 255) & ~(size_t)255;
    const size_t scale_bytes = ((size_t)n_nodes * sizeof(float) + 255) & ~(size_t)255;
    const size_t tab_bytes   = (size_t)n_nodes * D_FEAT;
    const bool   use_i8      = (off_bytes + scale_bytes + tab_bytes) <= ws_size;

    if (use_i8) {
        float*         scales = (float*)((char*)d_ws + off_bytes);
        unsigned char* tab    = (unsigned char*)((char*)d_ws + off_bytes + scale_bytes);

        const int qb = (n_nodes + 3) / 4;                    // quantize blocks
        const int ob = (n_gather + 255) / 256;               // offsets blocks
        prep_kernel<<<qb + ob, 256, 0, stream>>>(
            feat, tab, scales, n_nodes, qb, mids, n_gather, num_macro, offsets);

        pool_wave_i8_v2_kernel<<<(num_macro + 3) / 4, 256, 0, stream>>>(
            tab, scales, nids, offsets, out, num_macro);
    } else {
        seg_offsets_kernel<<<(n_gather + 255) / 256, 256, 0, stream>>>(
            mids, n_gather, num_macro, offsets);
        pool_mean_fp32_kernel<<<num_macro, 256, 0, stream>>>(feat, nids, offsets, out);
    }
}

// Round 2
// 144.090 us; speedup vs baseline: 1.1676x; 1.0173x over previous
//
#include <hip/hip_runtime.h>

#define D_FEAT 128
#define MAX_CHUNK 1024

// ---------------------------------------------------------------------------
// Fused prep (UNCHANGED — known good).
//   Blocks [0, qb):  per-row int8 quantization. 4 waves/block, one node row
//                    per wave: load 128 fp32 (float2/lane), butterfly absmax,
//                    q = rint(x * 127/absmax), write 128 B row + fp32 scale.
//   Blocks [qb, ..): segment offsets from the sorted macro ids.
__global__ __launch_bounds__(256)
void prep_kernel(const float* __restrict__ feat,
                 unsigned char* __restrict__ tab, float* __restrict__ scales,
                 int n_nodes, int qb,
                 const int* __restrict__ mids, int n_gather,
                 int num_macro, int* __restrict__ offsets) {
    if ((int)blockIdx.x < qb) {
        const int wave = threadIdx.x >> 6;
        const int lane = threadIdx.x & 63;
        const int row  = blockIdx.x * 4 + wave;
        if (row >= n_nodes) return;
        const float2 v = ((const float2*)feat)[(size_t)row * 64 + lane];
        float a = fmaxf(fabsf(v.x), fabsf(v.y));
        #pragma unroll
        for (int d = 1; d <= 32; d <<= 1) a = fmaxf(a, __shfl_xor(a, d, 64));
        const float inv = (a > 0.f) ? (127.f / a) : 0.f;
        const int q0 = (int)rintf(v.x * inv);
        const int q1 = (int)rintf(v.y * inv);
        const unsigned short p =
            (unsigned short)((q0 & 0xFF) | ((q1 & 0xFF) << 8));
        ((unsigned short*)tab)[(size_t)row * 64 + lane] = p;   // 128 B/row
        if (lane == 0) scales[row] = a * (1.f / 127.f);
    } else {
        const int i = ((int)blockIdx.x - qb) * 256 + (int)threadIdx.x;
        if (i >= n_gather) return;
        const int cur  = mids[i];
        const int prev = (i == 0) ? -1 : mids[i - 1];
        for (int m = prev + 1; m <= cur; ++m) offsets[m] = i;
        if (i == n_gather - 1) {
            for (int m = cur + 1; m <= num_macro; ++m) offsets[m] = n_gather;
        }
    }
}

// ---------------------------------------------------------------------------
// Pool v3: 4 rows per dwordx2 load, ONE WAVE per macro node.
//
// v2 post-mortem: VGPR_Count=20 proves the compiler serialized the "32-deep"
// batch (32 in-flight loads need >=64 VGPRs) — effective MLP was ~2-4, and
// per-row cost was ~1 VMEM + ~8 VALU. v3 restructures:
//   lane layout: slot = lane>>4 selects one of 4 rows, (lane&15)*8 = byte
//   offset. One global_load_dwordx2 covers 4 full 128 B rows ->
//   0.4M loads instead of 1.6M (same cache-line footprint, FETCH unchanged).
//   Per 4-row group: 2 ds_bpermute (idx+scale broadcast, shared vaddr)
//   + v_lshl_add + load. Tail rows masked branchlessly: the lane-clamped
//   scale vector is pre-zeroed for lanes >= rem, so dead rows fmac 0.
//   w[4]/s[4] fully unrolled (static indices) stay in registers -> 4 loads
//   genuinely in flight per wave; ~35 VGPR keeps occupancy high.
// Accumulator: 8 floats/lane = features (lane&15)*8..+8, partial over 4
// row-slots; epilogue = 2 shfl_xor hops, slot-0 lanes write 32 B each
// (coalesced 512 B row store). No LDS tiles, no barriers, no atomics.
__global__ __launch_bounds__(256)
void pool_wave_i8_v3_kernel(const unsigned char* __restrict__ tab,
                            const float* __restrict__ scales,
                            const int* __restrict__ nids,
                            const int* __restrict__ offsets,
                            float* __restrict__ out, int num_macro) {
    const int wave = threadIdx.x >> 6;
    const int m    = blockIdx.x * 4 + wave;
    if (m >= num_macro) return;

    const int lane = threadIdx.x & 63;
    const int slot = lane >> 4;            // which of 4 rows in a group
    const int co   = (lane & 15) << 3;     // byte offset within 128 B row

    const int start = offsets[m];
    const int cnt   = offsets[m + 1] - start;

    float acc[8];
    #pragma unroll
    for (int f = 0; f < 8; ++f) acc[f] = 0.f;

    for (int b0 = 0; b0 < cnt; b0 += 64) {
        const int rem = min(cnt - b0, 64);
        // one coalesced index load + one vector scale gather per chunk
        const int my = nids[start + b0 + ((lane < rem) ? lane : rem - 1)];
        float scz    = scales[my];                 // 400 KB array: L2-hit
        if (lane >= rem) scz = 0.f;                // kills tail contributions

        for (int k = 0; k < rem; k += 16) {        // super-step: 4 groups
            uint2 w[4];
            float s[4];
            #pragma unroll
            for (int j = 0; j < 4; ++j) {
                const int src = k + (j << 2) + slot;       // row within chunk
                const int idx = __shfl(my, src, 64);       // ds_bpermute
                s[j] = __shfl(scz, src, 64);               // shares vaddr
                w[j] = *(const uint2*)(tab + (((unsigned)idx << 7) + (unsigned)co));
            }
            #pragma unroll
            for (int j = 0; j < 4; ++j) {
                const unsigned lo = w[j].x;
                const unsigned hi = w[j].y;
                acc[0] += s[j] * (float)(signed char)( lo         & 0xFF);
                acc[1] += s[j] * (float)(signed char)((lo >> 8)   & 0xFF);
                acc[2] += s[j] * (float)(signed char)((lo >> 16)  & 0xFF);
                acc[3] += s[j] * (float)(signed char)( lo >> 24);
                acc[4] += s[j] * (float)(signed char)( hi         & 0xFF);
                acc[5] += s[j] * (float)(signed char)((hi >> 8)   & 0xFF);
                acc[6] += s[j] * (float)(signed char)((hi >> 16)  & 0xFF);
                acc[7] += s[j] * (float)(signed char)( hi >> 24);
            }
        }
    }

    // fold the 4 row-slots (lanes differing in bits 4,5 share a feature set)
    #pragma unroll
    for (int f = 0; f < 8; ++f) {
        acc[f] += __shfl_xor(acc[f], 16, 64);
        acc[f] += __shfl_xor(acc[f], 32, 64);
    }

    if (slot == 0) {
        const float inv = (cnt > 0) ? (1.0f / (float)cnt) : 0.0f;
        float* dst = out + (size_t)m * D_FEAT + co;   // co == feature index
        *(float4*)(dst)     = make_float4(acc[0] * inv, acc[1] * inv,
                                          acc[2] * inv, acc[3] * inv);
        *(float4*)(dst + 4) = make_float4(acc[4] * inv, acc[5] * inv,
                                          acc[6] * inv, acc[7] * inv);
    }
}

// ---------------------------------------------------------------------------
// Fallback (fp32 table, no shadow) — only if ws_size can't hold the tables.
__global__ __launch_bounds__(256)
void pool_mean_fp32_kernel(const float* __restrict__ feat,
                           const int* __restrict__ nids,
                           const int* __restrict__ offsets,
                           float* __restrict__ out) {
    const int m    = blockIdx.x;
    const int tid  = threadIdx.x;
    const int g    = tid >> 5;
    const int c4   = (tid & 31) << 2;

    const int start = offsets[m];
    const int cnt   = offsets[m + 1] - start;

    __shared__ int   s_idx[MAX_CHUNK];
    __shared__ float red[8][D_FEAT];

    float4 acc = make_float4(0.f, 0.f, 0.f, 0.f);
    for (int base = 0; base < cnt; base += MAX_CHUNK) {
        const int chunk = min(cnt - base, MAX_CHUNK);
        for (int t = tid; t < chunk; t += 256) s_idx[t] = nids[start + base + t];
        __syncthreads();
        int r = g;
        for (; r + 24 < chunk; r += 32) {
            const float4 v0 = *(const float4*)(feat + (size_t)s_idx[r]      * D_FEAT + c4);
            const float4 v1 = *(const float4*)(feat + (size_t)s_idx[r + 8]  * D_FEAT + c4);
            const float4 v2 = *(const float4*)(feat + (size_t)s_idx[r + 16] * D_FEAT + c4);
            const float4 v3 = *(const float4*)(feat + (size_t)s_idx[r + 24] * D_FEAT + c4);
            acc.x += v0.x + v1.x + v2.x + v3.x;
            acc.y += v0.y + v1.y + v2.y + v3.y;
            acc.z += v0.z + v1.z + v2.z + v3.z;
            acc.w += v0.w + v1.w + v2.w + v3.w;
        }
        for (; r < chunk; r += 8) {
            const float4 v = *(const float4*)(feat + (size_t)s_idx[r] * D_FEAT + c4);
            acc.x += v.x; acc.y += v.y; acc.z += v.z; acc.w += v.w;
        }
        __syncthreads();
    }

    red[g][c4 + 0] = acc.x;
    red[g][c4 + 1] = acc.y;
    red[g][c4 + 2] = acc.z;
    red[g][c4 + 3] = acc.w;
    __syncthreads();

    if (tid < D_FEAT) {
        float s = 0.f;
        #pragma unroll
        for (int k = 0; k < 8; ++k) s += red[k][tid];
        const float inv = (cnt > 0) ? (1.0f / (float)cnt) : 0.0f;
        out[(size_t)m * D_FEAT + tid] = s * inv;
    }
}

// Offsets-only prep for the fallback path.
__global__ __launch_bounds__(256)
void seg_offsets_kernel(const int* __restrict__ mids, int n_gather,
                        int num_macro, int* __restrict__ offsets) {
    const int i = blockIdx.x * blockDim.x + threadIdx.x;
    if (i >= n_gather) return;
    const int cur  = mids[i];
    const int prev = (i == 0) ? -1 : mids[i - 1];
    for (int m = prev + 1; m <= cur; ++m) offsets[m] = i;
    if (i == n_gather - 1) {
        for (int m = cur + 1; m <= num_macro; ++m) offsets[m] = n_gather;
    }
}

extern "C" void kernel_launch(void* const* d_in, const int* in_sizes, int n_in,
                              void* d_out, int out_size, void* d_ws, size_t ws_size,
                              hipStream_t stream) {
    const float* feat = (const float*)d_in[0];   // [n_nodes, 128] fp32
    const int*   nids = (const int*)d_in[1];     // [n_gather] int32
    const int*   mids = (const int*)d_in[2];     // [n_gather] int32, sorted
    float*       out  = (float*)d_out;           // [num_macro, 128] fp32

    const int n_gather  = in_sizes[1];
    const int num_macro = out_size / D_FEAT;
    const int n_nodes   = in_sizes[0] / D_FEAT;

    // d_ws: [offsets (num_macro+1) ints][scales n_nodes fp32][int8 table], 256-aligned
    int* offsets = (int*)d_ws;
    const size_t off_bytes   = ((size_t)(num_macro + 1) * sizeof(int) + 255) & ~(size_t)255;
    const size_t scale_bytes = ((size_t)n_nodes * sizeof(float) + 255) & ~(size_t)255;
    const size_t tab_bytes   = (size_t)n_nodes * D_FEAT;
    const bool   use_i8      = (off_bytes + scale_bytes + tab_bytes) <= ws_size;

    if (use_i8) {
        float*         scales = (float*)((char*)d_ws + off_bytes);
        unsigned char* tab    = (unsigned char*)((char*)d_ws + off_bytes + scale_bytes);

        const int qb = (n_nodes + 3) / 4;                    // quantize blocks
        const int ob = (n_gather + 255) / 256;               // offsets blocks
        prep_kernel<<<qb + ob, 256, 0, stream>>>(
            feat, tab, scales, n_nodes, qb, mids, n_gather, num_macro, offsets);

        pool_wave_i8_v3_kernel<<<(num_macro + 3) / 4, 256, 0, stream>>>(
            tab, scales, nids, offsets, out, num_macro);
    } else {
        seg_offsets_kernel<<<(n_gather + 255) / 256, 256, 0, stream>>>(
            mids, n_gather, num_macro, offsets);
        pool_mean_fp32_kernel<<<num_macro, 256, 0, stream>>>(feat, nids, offsets, out);
    }
}